// Round 1
// baseline (737.537 us; speedup 1.0000x reference)
//
#include <hip/hip_runtime.h>
#include <hip/hip_bf16.h>

#define BDIM 128  // batch size, fixed by problem

// ---------------------------------------------------------------------------
// Kernel 1: transpose x (B=128, N) row-major -> xT (N, 128) row-major.
// Tile: 64 n x 128 b staged in LDS (padded +1 word -> conflict-free).
// Reads coalesced along n, writes coalesced along b (512B rows).
// ---------------------------------------------------------------------------
__global__ __launch_bounds__(256) void transpose_kernel(
    const float* __restrict__ x, float* __restrict__ xT, int N) {
  __shared__ float tile[64][BDIM + 1];
  const int tid = threadIdx.x;
  const int n0  = blockIdx.x * 64;

  // load phase: tn = lane-within-64 walks n (coalesced), 4 b-rows at a time
  const int tn  = tid & 63;
  const int tb0 = tid >> 6;              // 0..3
  const int n   = n0 + tn;
  if (n < N) {
    for (int b = tb0; b < BDIM; b += 4)
      tile[tn][b] = x[(size_t)b * N + n];
  }
  __syncthreads();

  // store phase: tbb walks b (coalesced 512B), 2 n-rows at a time
  const int tbb = tid & 127;
  const int tn2 = tid >> 7;              // 0..1
  for (int nl = tn2; nl < 64; nl += 2) {
    if (n0 + nl < N)
      xT[(size_t)(n0 + nl) * BDIM + tbb] = tile[nl][tbb];
  }
}

// ---------------------------------------------------------------------------
// Kernel 2: edge interactions. One wave owns a contiguous edge range; each
// lane owns 2 batch elements (float2). Per edge: two coalesced 512B row
// reads of xT + uniform {i, j, J}. Block-reduce 4 waves -> partials row.
// ---------------------------------------------------------------------------
__global__ __launch_bounds__(256) void edge_kernel(
    const float* __restrict__ xT, const float* __restrict__ J,
    const int* __restrict__ ei, const int* __restrict__ ej,
    float* __restrict__ partials, int E, int edges_per_wave) {
  const int tid  = threadIdx.x;
  const int wave = tid >> 6;
  const int lane = tid & 63;
  const int boff = lane * 2;

  const int gwave = blockIdx.x * 4 + wave;
  int start = gwave * edges_per_wave;
  int end   = start + edges_per_wave;
  if (start > E) start = E;
  if (end   > E) end   = E;

  float accx = 0.f, accy = 0.f;
#pragma unroll 4
  for (int e = start; e < end; ++e) {
    const int i = ei[e];
    const int j = ej[e];
    const float Jv = J[e];
    const float2 xi = *(const float2*)&xT[i * BDIM + boff];
    const float2 xj = *(const float2*)&xT[j * BDIM + boff];
    accx += (xi.x * xj.x) * Jv;
    accy += (xi.y * xj.y) * Jv;
  }

  __shared__ float red[4][BDIM];
  red[wave][boff]     = accx;
  red[wave][boff + 1] = accy;
  __syncthreads();
  if (tid < BDIM) {
    float s = red[0][tid] + red[1][tid] + red[2][tid] + red[3][tid];
    partials[(size_t)blockIdx.x * BDIM + tid] = s;
  }
}

// ---------------------------------------------------------------------------
// Kernel 3: h-term  sum_n x[b,n]*h[n], reading xT rows (coalesced 512B).
// Grid-stride over n per wave; block-reduce -> partials row.
// ---------------------------------------------------------------------------
__global__ __launch_bounds__(256) void h_kernel(
    const float* __restrict__ xT, const float* __restrict__ h,
    float* __restrict__ partials, int N) {
  const int tid  = threadIdx.x;
  const int wave = tid >> 6;
  const int lane = tid & 63;
  const int boff = lane * 2;

  const int gwave = blockIdx.x * 4 + wave;
  const int stride = gridDim.x * 4;

  float accx = 0.f, accy = 0.f;
  for (int n = gwave; n < N; n += stride) {
    const float hv = h[n];
    const float2 xv = *(const float2*)&xT[n * BDIM + boff];
    accx += xv.x * hv;
    accy += xv.y * hv;
  }

  __shared__ float red[4][BDIM];
  red[wave][boff]     = accx;
  red[wave][boff + 1] = accy;
  __syncthreads();
  if (tid < BDIM) {
    float s = red[0][tid] + red[1][tid] + red[2][tid] + red[3][tid];
    partials[(size_t)blockIdx.x * BDIM + tid] = s;
  }
}

// ---------------------------------------------------------------------------
// Kernel 4: deterministic final reduce over all partial rows; overwrites out.
// ---------------------------------------------------------------------------
__global__ __launch_bounds__(128) void reduce_kernel(
    const float* __restrict__ partials, float* __restrict__ out, int rows) {
  const int b = threadIdx.x;  // 0..127
  float s = 0.f;
  for (int r = 0; r < rows; ++r)
    s += partials[(size_t)r * BDIM + b];
  out[b] = s;
}

extern "C" void kernel_launch(void* const* d_in, const int* in_sizes, int n_in,
                              void* d_out, int out_size, void* d_ws, size_t ws_size,
                              hipStream_t stream) {
  const float* x  = (const float*)d_in[0];
  const float* h  = (const float*)d_in[1];
  const float* J  = (const float*)d_in[2];
  const int*   ei = (const int*)d_in[3];
  const int*   ej = (const int*)d_in[4];
  float* out = (float*)d_out;

  const int N = in_sizes[1];   // 50000
  const int E = in_sizes[2];   // 1600000

  // workspace layout: xT (N*128 floats) | partials ((EBLK+HBLK)*128 floats)
  float* xT = (float*)d_ws;
  const int EBLK = 2048;
  const int HBLK = 128;
  float* partials = xT + (size_t)N * BDIM;

  // 1) transpose
  const int tblocks = (N + 63) / 64;
  transpose_kernel<<<tblocks, 256, 0, stream>>>(x, xT, N);

  // 2) edge interactions
  const int epw = (E + EBLK * 4 - 1) / (EBLK * 4);
  edge_kernel<<<EBLK, 256, 0, stream>>>(xT, J, ei, ej, partials, E, epw);

  // 3) h-term
  h_kernel<<<HBLK, 256, 0, stream>>>(xT, h, partials + (size_t)EBLK * BDIM, N);

  // 4) final deterministic reduce (overwrites d_out)
  reduce_kernel<<<1, BDIM, 0, stream>>>(partials, out, EBLK + HBLK);
}

// Round 2
// 252.320 us; speedup vs baseline: 2.9230x; 2.9230x over previous
//
#include <hip/hip_runtime.h>
#include <hip/hip_bf16.h>

#define BDIM 128  // batch size, fixed by problem

// ---------------------------------------------------------------------------
// Kernel 1: transpose x (B=128, N) row-major -> xT (N, 128) row-major.
// Tile: 64 n x 128 b staged in LDS (padded +1 word -> conflict-free).
// Reads coalesced along n, writes coalesced along b (512B rows).
// ---------------------------------------------------------------------------
__global__ __launch_bounds__(256) void transpose_kernel(
    const float* __restrict__ x, float* __restrict__ xT, int N) {
  __shared__ float tile[64][BDIM + 1];
  const int tid = threadIdx.x;
  const int n0  = blockIdx.x * 64;

  // load phase: tn = lane-within-64 walks n (coalesced), 4 b-rows at a time
  const int tn  = tid & 63;
  const int tb0 = tid >> 6;              // 0..3
  const int n   = n0 + tn;
  if (n < N) {
    for (int b = tb0; b < BDIM; b += 4)
      tile[tn][b] = x[(size_t)b * N + n];
  }
  __syncthreads();

  // store phase: tbb walks b (coalesced 512B), 2 n-rows at a time
  const int tbb = tid & 127;
  const int tn2 = tid >> 7;              // 0..1
  for (int nl = tn2; nl < 64; nl += 2) {
    if (n0 + nl < N)
      xT[(size_t)(n0 + nl) * BDIM + tbb] = tile[nl][tbb];
  }
}

// ---------------------------------------------------------------------------
// Kernel 2: edge interactions. One wave owns a contiguous edge range; each
// lane owns 2 batch elements (float2). Per edge: two coalesced 512B row
// reads of xT + uniform {i, j, J} (wave-uniform -> scalar loads).
// Block-reduce 4 waves -> one partials row per block.
// ---------------------------------------------------------------------------
__global__ __launch_bounds__(256) void edge_kernel(
    const float* __restrict__ xT, const float* __restrict__ J,
    const int* __restrict__ ei, const int* __restrict__ ej,
    float* __restrict__ partials, int E, int edges_per_wave) {
  const int tid  = threadIdx.x;
  const int wave = tid >> 6;
  const int lane = tid & 63;
  const int boff = lane * 2;

  const int gwave = blockIdx.x * 4 + wave;
  int start = gwave * edges_per_wave;
  int end   = start + edges_per_wave;
  if (start > E) start = E;
  if (end   > E) end   = E;

  float accx = 0.f, accy = 0.f;
#pragma unroll 4
  for (int e = start; e < end; ++e) {
    const int i = ei[e];
    const int j = ej[e];
    const float Jv = J[e];
    const float2 xi = *(const float2*)&xT[i * BDIM + boff];
    const float2 xj = *(const float2*)&xT[j * BDIM + boff];
    accx += (xi.x * xj.x) * Jv;
    accy += (xi.y * xj.y) * Jv;
  }

  __shared__ float red[4][BDIM];
  red[wave][boff]     = accx;
  red[wave][boff + 1] = accy;
  __syncthreads();
  if (tid < BDIM) {
    float s = red[0][tid] + red[1][tid] + red[2][tid] + red[3][tid];
    partials[(size_t)blockIdx.x * BDIM + tid] = s;
  }
}

// ---------------------------------------------------------------------------
// Kernel 3: h-term  sum_n x[b,n]*h[n], reading xT rows (coalesced 512B).
// Grid-stride over n per wave; block-reduce -> partials row.
// ---------------------------------------------------------------------------
__global__ __launch_bounds__(256) void h_kernel(
    const float* __restrict__ xT, const float* __restrict__ h,
    float* __restrict__ partials, int N) {
  const int tid  = threadIdx.x;
  const int wave = tid >> 6;
  const int lane = tid & 63;
  const int boff = lane * 2;

  const int gwave = blockIdx.x * 4 + wave;
  const int stride = gridDim.x * 4;

  float accx = 0.f, accy = 0.f;
  for (int n = gwave; n < N; n += stride) {
    const float hv = h[n];
    const float2 xv = *(const float2*)&xT[n * BDIM + boff];
    accx += xv.x * hv;
    accy += xv.y * hv;
  }

  __shared__ float red[4][BDIM];
  red[wave][boff]     = accx;
  red[wave][boff + 1] = accy;
  __syncthreads();
  if (tid < BDIM) {
    float s = red[0][tid] + red[1][tid] + red[2][tid] + red[3][tid];
    partials[(size_t)blockIdx.x * BDIM + tid] = s;
  }
}

// ---------------------------------------------------------------------------
// Kernel 4: parallel column-sum over partial rows (coalesced, deterministic).
// Each block: 256 threads = 2 row-lanes x 128 b. Grid-stride over rows,
// LDS-combine the 2 sub-rows, emit one row per block.
// Called twice: rows -> gridDim rows -> (gridDim=1) final 128 outputs.
// ---------------------------------------------------------------------------
__global__ __launch_bounds__(256) void reduce_kernel(
    const float* __restrict__ partials, float* __restrict__ out, int rows) {
  const int b  = threadIdx.x & 127;
  const int rg = threadIdx.x >> 7;   // 0..1
  float acc = 0.f;
  for (int r = blockIdx.x * 2 + rg; r < rows; r += gridDim.x * 2)
    acc += partials[(size_t)r * BDIM + b];
  __shared__ float red[2][BDIM];
  red[rg][b] = acc;
  __syncthreads();
  if (threadIdx.x < BDIM)
    out[(size_t)blockIdx.x * BDIM + threadIdx.x] =
        red[0][threadIdx.x] + red[1][threadIdx.x];
}

extern "C" void kernel_launch(void* const* d_in, const int* in_sizes, int n_in,
                              void* d_out, int out_size, void* d_ws, size_t ws_size,
                              hipStream_t stream) {
  const float* x  = (const float*)d_in[0];
  const float* h  = (const float*)d_in[1];
  const float* J  = (const float*)d_in[2];
  const int*   ei = (const int*)d_in[3];
  const int*   ej = (const int*)d_in[4];
  float* out = (float*)d_out;

  const int N = in_sizes[1];   // 50000
  const int E = in_sizes[2];   // 1600000

  // workspace layout: xT (N*128) | partials ((EBLK+HBLK)*128) | partials2 (64*128)
  float* xT = (float*)d_ws;
  const int EBLK = 2048;
  const int HBLK = 128;
  const int ROWS = EBLK + HBLK;
  float* partials  = xT + (size_t)N * BDIM;
  float* partials2 = partials + (size_t)ROWS * BDIM;

  // 1) transpose
  const int tblocks = (N + 63) / 64;
  transpose_kernel<<<tblocks, 256, 0, stream>>>(x, xT, N);

  // 2) edge interactions
  const int epw = (E + EBLK * 4 - 1) / (EBLK * 4);
  edge_kernel<<<EBLK, 256, 0, stream>>>(xT, J, ei, ej, partials, E, epw);

  // 3) h-term
  h_kernel<<<HBLK, 256, 0, stream>>>(xT, h, partials + (size_t)EBLK * BDIM, N);

  // 4) two-stage deterministic reduce (overwrites d_out)
  reduce_kernel<<<64, 256, 0, stream>>>(partials, partials2, ROWS);
  reduce_kernel<<<1, 256, 0, stream>>>(partials2, out, 64);
}